// Round 9
// baseline (170.218 us; speedup 1.0000x reference)
//
#include <hip/hip_runtime.h>
#include <math.h>

typedef unsigned short ushort_t;
typedef __attribute__((ext_vector_type(8))) short short8;
typedef __attribute__((ext_vector_type(4))) float float4v;

// Problem constants
#define NB 4
#define C 64
#define CR 32
#define HW 2304
#define LTOT 7470
#define LPAD 7472
#define NSEG 10
#define SEG 768     // segs 0-8 = 768 (12 chunks), seg 9 = 558 (8 full + 46 tail)
#define LOG2E 1.44269504088896f

// ---- workspace float offsets ----
// Region A (aliased): conv phase: XT bf16 [33000 px][64 ic] = 2112000 shorts
//                     attn phase: YP + LP
#define YP_F 0            // NSEG*4*2304*64 = 5898240
#define LP_F 5898240      // NSEG*4*2304 = 92160 (end 5990400)
// Persistent region
#define MBBF_F   8985600  // bf16 queries (log2e-scaled) [n][q][32]   294912 sh
#define KEYBF_F  9133056  // bf16 keys [n][l][32]                     956160 sh
#define RAWTBF_F 9611136  // bf16 V^T  [n][c][LPAD]                   1912832 sh
#define WPK_F    10567552 // packed key weights 36 frags*512 sh
#define WPQ_F    10576768 // packed query weights 36*512
#define WPV_F    10585984 // packed value weights 8*512 (end 10588032 = 42.4 MB)

static __device__ __forceinline__ ushort_t f2bf(float f) {
  union { float f; unsigned u; } v; v.f = f;
  unsigned r = v.u + 0x7FFF + ((v.u >> 16) & 1);
  return (ushort_t)(r >> 16);
}

__device__ __forceinline__ float cubicw(float d) {
  float ad = fabsf(d);
  float w1 = (1.25f * ad - 2.25f) * ad * ad + 1.0f;
  float w2 = ((-0.75f * ad + 3.75f) * ad - 6.0f) * ad + 3.0f;
  return ad <= 1.0f ? w1 : (ad < 2.0f ? w2 : 0.0f);
}

// ================= k_prep: ring-zero | pad0 | resize | wpack =================
__global__ __launch_bounds__(256) void k_prep(const float* __restrict__ x,
    const float* __restrict__ wm, const float* __restrict__ wb,
    const float* __restrict__ wa, ushort_t* __restrict__ xt,
    ushort_t* __restrict__ wpk, ushort_t* __restrict__ wpq,
    ushort_t* __restrict__ wpv) {
  __shared__ float tile[64][49];
  int bx = blockIdx.x, t = threadIdx.x;

  if (bx < 98) {
    int item = bx * 256 + t;
    if (item < 24960) {
      int pxslot = item >> 3, c8 = item & 7;
      int n = pxslot / 780, rr = pxslot % 780;
      int Dp, PDD, pixb, r;
      if (rr < 196)      { Dp = 50; PDD = 2500; pixb = 0;     r = rr; }
      else if (rr < 372) { Dp = 45; PDD = 2025; pixb = 10000; r = rr - 196; }
      else if (rr < 528) { Dp = 40; PDD = 1600; pixb = 18100; r = rr - 372; }
      else if (rr < 664) { Dp = 35; PDD = 1225; pixb = 24500; r = rr - 528; }
      else               { Dp = 30; PDD = 900;  pixb = 29400; r = rr - 664; }
      int py, px;
      if (r < Dp)            { py = 0; px = r; }
      else if (r < 2 * Dp)   { py = Dp - 1; px = r - Dp; }
      else { int s = r - 2 * Dp; py = 1 + (s >> 1); px = (s & 1) ? Dp - 1 : 0; }
      uint4 z = {0u, 0u, 0u, 0u};
      *(uint4*)(xt + ((size_t)(pixb + n * PDD + py * Dp + px)) * 64 + c8 * 8) = z;
    }
  } else if (bx < 290) {
    int pb = bx - 98;
    int py = pb % 48, n = pb / 48;
#pragma unroll
    for (int i = 0; i < 12; i++) {
      int idx = i * 256 + t;
      int c = idx / 48, px = idx % 48;
      tile[c][px] = x[(size_t)(n * 64 + c) * HW + py * 48 + px];
    }
    __syncthreads();
#pragma unroll
    for (int i = 0; i < 12; i++) {
      int idx = i * 256 + t;
      int c = idx & 63, px = idx >> 6;
      xt[(size_t)(n * 2500 + (py + 1) * 50 + px + 1) * 64 + c] = f2bf(tile[c][px]);
    }
  } else if (bx < 5456) {
    int tid = (bx - 290) * 256 + t;
    if (tid >= 1322496) return;
    int D, Dp, PDD, rem, pixb;
    if (tid < 473344)       { D = 43; Dp = 45; PDD = 2025; rem = tid;           pixb = 10000; }
    else if (tid < 843008)  { D = 38; Dp = 40; PDD = 1600; rem = tid - 473344;  pixb = 18100; }
    else if (tid < 1121792) { D = 33; Dp = 35; PDD = 1225; rem = tid - 843008;  pixb = 24500; }
    else                    { D = 28; Dp = 30; PDD = 900;  rem = tid - 1121792; pixb = 29400; }
    int DD = D * D;
    int pix = rem % DD, nc = rem / DD;
    int py = pix / D, px = pix % D;
    float scale = 48.0f / (float)D;
    float sy = ((float)py + 0.5f) * scale - 0.5f;
    float sx = ((float)px + 0.5f) * scale - 0.5f;
    float y0f = floorf(sy), x0f = floorf(sx);
    int y0 = (int)y0f, x0 = (int)x0f;
    float ty = sy - y0f, tx = sx - x0f;
    float wy[4], wxv[4];
#pragma unroll
    for (int k = 0; k < 4; k++) {
      wy[k]  = cubicw(ty - (float)(k - 1));
      wxv[k] = cubicw(tx - (float)(k - 1));
    }
    const float* src = x + (size_t)nc * HW;
    float acc = 0.f;
#pragma unroll
    for (int dy = 0; dy < 4; ++dy) {
      int iy = min(max(y0 - 1 + dy, 0), 47);
      const float* row = src + iy * 48;
      float a = 0.f;
#pragma unroll
      for (int dx = 0; dx < 4; ++dx) {
        int ix = min(max(x0 - 1 + dx, 0), 47);
        a = fmaf(wxv[dx], row[ix], a);
      }
      acc = fmaf(wy[dy], a, acc);
    }
    int n = nc >> 6, c = nc & 63;
    xt[(size_t)(pixb + n * PDD + (py + 1) * Dp + (px + 1)) * 64 + c] = f2bf(acc);
  } else {
    int tid = (bx - 5456) * 256 + t;
    if (tid >= 5120) return;
    int lane = tid & 63, col = lane & 15, kg = lane >> 4;
    if (tid < 4608) {
      int f = (tid >> 6) % 36;
      bool isq = tid >= 2304;
      int tap = f >> 2, half = (f >> 1) & 1, crt = f & 1;
      int cr = crt * 16 + col;
      int ic0 = half * 32 + kg * 8;
      const float* w = isq ? wb : wm;
      short8 v;
#pragma unroll
      for (int j = 0; j < 8; j++) v[j] = (short)f2bf(w[cr * 576 + (ic0 + j) * 9 + tap]);
      *(short8*)((isq ? wpq : wpk) + (size_t)f * 512 + lane * 8) = v;
    } else {
      int id = tid - 4608;
      int f = id >> 6;
      int half = f >> 2, vt = f & 3;
      int c = vt * 16 + col, ic0 = half * 32 + kg * 8;
      short8 v;
#pragma unroll
      for (int j = 0; j < 8; j++) v[j] = (short)f2bf(wa[c * 64 + ic0 + j]);
      *(short8*)(wpv + (size_t)f * 512 + lane * 8) = v;
    }
  }
}

// ================= all convs as implicit-GEMM MFMA =================
__global__ __launch_bounds__(256) void k_conv(const ushort_t* __restrict__ xt,
    const ushort_t* __restrict__ wpk, const ushort_t* __restrict__ wpq,
    const ushort_t* __restrict__ wpv, const float* __restrict__ bm,
    const float* __restrict__ bb, const float* __restrict__ ba,
    ushort_t* __restrict__ keybf, ushort_t* __restrict__ mbbf,
    ushort_t* __restrict__ rawtbf) {
  int t = threadIdx.x;
  int unit = blockIdx.x * 4 + (t >> 6);
  if (unit >= 938) return;
  int lane = t & 63, col = lane & 15, quad = lane >> 4;
  int n = blockIdx.y;
  int tile = unit >> 1, crt = unit & 1;
  int D, Dp, PDD, DD, pixb, lb, tloc;
  if (tile < 144)      { D = 48; Dp = 50; PDD = 2500; DD = 2304; pixb = 0;     lb = 0;    tloc = tile; }
  else if (tile < 260) { D = 43; Dp = 45; PDD = 2025; DD = 1849; pixb = 10000; lb = 2304; tloc = tile - 144; }
  else if (tile < 351) { D = 38; Dp = 40; PDD = 1600; DD = 1444; pixb = 18100; lb = 4153; tloc = tile - 260; }
  else if (tile < 420) { D = 33; Dp = 35; PDD = 1225; DD = 1089; pixb = 24500; lb = 5597; tloc = tile - 351; }
  else                 { D = 28; Dp = 30; PDD = 900;  DD = 784;  pixb = 29400; lb = 6686; tloc = tile - 420; }
  bool lvl0 = (tile < 144);

  int p = tloc * 16 + col;
  int pv = min(p, DD - 1);
  int py = pv / D, px = pv - py * D;
  const ushort_t* xb = xt + ((size_t)(pixb + n * PDD + (py + 1) * Dp + (px + 1))) * 64 + quad * 8;

  float4v Dk = {0.f, 0.f, 0.f, 0.f};
  float4v Dq = {0.f, 0.f, 0.f, 0.f};
  float4v Dv0 = {0.f, 0.f, 0.f, 0.f};
  float4v Dv1 = {0.f, 0.f, 0.f, 0.f};

#pragma unroll
  for (int dy = -1; dy <= 1; dy++) {
#pragma unroll
    for (int dx = -1; dx <= 1; dx++) {
      int tap = (dy + 1) * 3 + (dx + 1);
      const ushort_t* ab = xb + (dy * Dp + dx) * 64;
#pragma unroll
      for (int half = 0; half < 2; half++) {
        short8 A = *(const short8*)(ab + half * 32);
        int f = (tap * 2 + half) * 2 + crt;
        short8 Bk = *(const short8*)(wpk + (size_t)f * 512 + lane * 8);
        Dk = __builtin_amdgcn_mfma_f32_16x16x32_bf16(A, Bk, Dk, 0, 0, 0);
        if (lvl0) {
          short8 Bq = *(const short8*)(wpq + (size_t)f * 512 + lane * 8);
          Dq = __builtin_amdgcn_mfma_f32_16x16x32_bf16(A, Bq, Dq, 0, 0, 0);
        }
        if (tap == 4) {
          short8 Bv0 = *(const short8*)(wpv + (size_t)(half * 4 + crt * 2) * 512 + lane * 8);
          short8 Bv1 = *(const short8*)(wpv + (size_t)(half * 4 + crt * 2 + 1) * 512 + lane * 8);
          Dv0 = __builtin_amdgcn_mfma_f32_16x16x32_bf16(A, Bv0, Dv0, 0, 0, 0);
          Dv1 = __builtin_amdgcn_mfma_f32_16x16x32_bf16(A, Bv1, Dv1, 0, 0, 0);
        }
      }
    }
  }

  float biask = bm[crt * 16 + col];
  float biasq = bb[crt * 16 + col];
  float biasv0 = ba[crt * 32 + col];
  float biasv1 = ba[crt * 32 + 16 + col];
  int prow = tloc * 16 + quad * 4;
#pragma unroll
  for (int r = 0; r < 4; r++) {
    if (prow + r < DD) {
      int l = lb + prow + r;
      keybf[(size_t)(n * LTOT + l) * 32 + crt * 16 + col] = f2bf(Dk[r] + biask);
      if (lvl0) mbbf[(size_t)(n * HW + l) * 32 + crt * 16 + col] = f2bf((Dq[r] + biasq) * LOG2E);
      rawtbf[(size_t)(n * 64 + crt * 32 + col) * LPAD + l] = f2bf(Dv0[r] + biasv0);
      rawtbf[(size_t)(n * 64 + crt * 32 + 16 + col) * LPAD + l] = f2bf(Dv1[r] + biasv1);
    }
  }
}

// ================= MFMA flash attention v3: barrier-free =================
// grid (18 q-tiles of 128, 4 n, NSEG). Block 256 = 4 waves; wave owns 32 q.
// K and V fragments read DIRECTLY from global (L2-resident, register
// prefetch). LDS holds only the wave-private P buffer -> no __syncthreads
// anywhere; waves fully decoupled.
__global__ __launch_bounds__(256) void k_attn(const ushort_t* __restrict__ mb,
    const ushort_t* __restrict__ keyb, const ushort_t* __restrict__ rawt,
    float* __restrict__ Yp, float* __restrict__ lp) {
  __shared__ __align__(16) ushort_t Pq[4][32 * 72];  // per-wave P[32 q][72]

  int t = threadIdx.x;
  int n = blockIdx.y, seg = blockIdx.z;
  int lane = t & 63, wv = t >> 6;
  int col = lane & 15, quad = lane >> 4;
  int qb = blockIdx.x * 128 + wv * 32;
  int l_begin = seg * SEG;
  int l_end = min(l_begin + SEG, LTOT);
  int nfull = (l_end - l_begin) >> 6;
  int rem = (l_end - l_begin) & 63;
  int nch = nfull + (rem ? 1 : 0);

  const ushort_t* keyn = keyb + (size_t)n * LTOT * CR;
  const ushort_t* rawn = rawt + (size_t)n * C * LPAD;

  short8 qA0 = *(const short8*)(mb + ((size_t)(n * HW + qb + col)) * CR + quad * 8);
  short8 qA1 = *(const short8*)(mb + ((size_t)(n * HW + qb + 16 + col)) * CR + quad * 8);

  float4v Y0[4], Y1[4];
#pragma unroll
  for (int ct = 0; ct < 4; ct++)
#pragma unroll
    for (int r = 0; r < 4; r++) { Y0[ct][r] = 0.f; Y1[ct][r] = 0.f; }
  float ls0 = 0.f, ls1 = 0.f;
  const float4v zero4 = {0.f, 0.f, 0.f, 0.f};
  ushort_t* Pw = Pq[wv];

  // per-lane global offsets
  const ushort_t* kbase = keyn + (size_t)(l_begin + col) * CR + quad * 8;
  size_t vrow = (size_t)col * LPAD + quad * 8;   // + ct*16*LPAD + kt*32

  for (int ch = 0; ch < nch; ++ch) {
    int l0 = l_begin + ch * 64;
    bool tail = (rem != 0) && (ch == nfull);

    // ---- prefetch K (4) and V (8) fragments from global ----
    short8 kf[4];
#pragma unroll
    for (int tt = 0; tt < 4; tt++)
      kf[tt] = *(const short8*)(kbase + (size_t)(ch * 64 + tt * 16) * CR);
    short8 bv[8];
#pragma unroll
    for (int kt = 0; kt < 2; kt++)
#pragma unroll
      for (int ct = 0; ct < 4; ct++)
        bv[(kt << 2) | ct] = *(const short8*)(rawn + vrow + (size_t)ct * 16 * LPAD + l0 + kt * 32);

    // ---- S^T = K·Q^T, p = exp2, P -> wave-private LDS ----
#pragma unroll
    for (int tt = 0; tt < 4; tt++) {
      float4v S0 = __builtin_amdgcn_mfma_f32_16x16x32_bf16(kf[tt], qA0, zero4, 0, 0, 0);
      float4v S1 = __builtin_amdgcn_mfma_f32_16x16x32_bf16(kf[tt], qA1, zero4, 0, 0, 0);
      int lbase = tt * 16 + quad * 4;
      float p0[4], p1[4];
#pragma unroll
      for (int r = 0; r < 4; r++) {
        bool ok = !tail || (lbase + r < rem);
        float a = __builtin_amdgcn_exp2f(S0[r]);
        float b = __builtin_amdgcn_exp2f(S1[r]);
        p0[r] = ok ? a : 0.f;
        p1[r] = ok ? b : 0.f;
        ls0 += p0[r];
        ls1 += p1[r];
      }
      union { float f; unsigned u; } c0, c1;
      uint2 w;
      c0.f = p0[0]; c1.f = p0[1];
      w.x = ((c0.u + 0x8000u) >> 16) | ((c1.u + 0x8000u) & 0xFFFF0000u);
      c0.f = p0[2]; c1.f = p0[3];
      w.y = ((c0.u + 0x8000u) >> 16) | ((c1.u + 0x8000u) & 0xFFFF0000u);
      *(uint2*)&Pw[col * 72 + lbase] = w;
      c0.f = p1[0]; c1.f = p1[1];
      w.x = ((c0.u + 0x8000u) >> 16) | ((c1.u + 0x8000u) & 0xFFFF0000u);
      c0.f = p1[2]; c1.f = p1[3];
      w.y = ((c0.u + 0x8000u) >> 16) | ((c1.u + 0x8000u) & 0xFFFF0000u);
      *(uint2*)&Pw[(16 + col) * 72 + lbase] = w;
    }

    // ---- PV: Y += P·V (P read back as A-frags; V already in registers) ----
#pragma unroll
    for (int kt = 0; kt < 2; kt++) {
      short8 a0 = *(const short8*)&Pw[col * 72 + kt * 32 + quad * 8];
      short8 a1 = *(const short8*)&Pw[(16 + col) * 72 + kt * 32 + quad * 8];
#pragma unroll
      for (int ct = 0; ct < 4; ct++) {
        short8 bV = bv[(kt << 2) | ct];
        Y0[ct] = __builtin_amdgcn_mfma_f32_16x16x32_bf16(a0, bV, Y0[ct], 0, 0, 0);
        Y1[ct] = __builtin_amdgcn_mfma_f32_16x16x32_bf16(a1, bV, Y1[ct], 0, 0, 0);
      }
    }
  }

  ls0 += __shfl_xor(ls0, 16); ls0 += __shfl_xor(ls0, 32);
  ls1 += __shfl_xor(ls1, 16); ls1 += __shfl_xor(ls1, 32);

  float* yo = Yp + ((size_t)(seg * NB + n) * HW + qb) * C;
#pragma unroll
  for (int ct = 0; ct < 4; ct++)
#pragma unroll
    for (int r = 0; r < 4; r++) {
      yo[(quad * 4 + r) * C + ct * 16 + col] = Y0[ct][r];
      yo[(16 + quad * 4 + r) * C + ct * 16 + col] = Y1[ct][r];
    }
  if (quad == 0) {
    int base = (seg * NB + n) * HW + qb;
    lp[base + col] = ls0;
    lp[base + 16 + col] = ls1;
  }
}

// ================= combine segment partials + residual (float4) =================
__global__ void k_combine(const float* __restrict__ x, const float* __restrict__ ws,
                          float* __restrict__ out) {
  int idx = blockIdx.x * 256 + threadIdx.x;   // 147456 = 4n * 16c4 * 2304q
  int n = idx / 36864;
  int rm = idx - n * 36864;
  int c4 = rm / HW;
  int q = rm - c4 * HW;
  const float* Yv = ws + YP_F;
  const float* lpv = ws + LP_F;
  int i0 = n * HW + q;
  float den = 0.f;
  float4v num = {0.f, 0.f, 0.f, 0.f};
#pragma unroll
  for (int s = 0; s < NSEG; s++) {
    int base = s * NB * HW + i0;
    float4v yv = *(const float4v*)(Yv + (size_t)base * C + c4 * 4);
    num += yv;
    den += lpv[base];
  }
  float inv = 1.0f / den;
  int ob = (n * C + c4 * 4) * HW + q;
  out[ob]          = num[0] * inv + x[ob];
  out[ob + HW]     = num[1] * inv + x[ob + HW];
  out[ob + 2 * HW] = num[2] * inv + x[ob + 2 * HW];
  out[ob + 3 * HW] = num[3] * inv + x[ob + 3 * HW];
}

extern "C" void kernel_launch(void* const* d_in, const int* in_sizes, int n_in,
                              void* d_out, int out_size, void* d_ws, size_t ws_size,
                              hipStream_t stream) {
  const float* x  = (const float*)d_in[0];
  const float* wb = (const float*)d_in[1];
  const float* bb = (const float*)d_in[2];
  const float* wm = (const float*)d_in[3];
  const float* bm = (const float*)d_in[4];
  const float* wa = (const float*)d_in[5];
  const float* ba = (const float*)d_in[6];
  float* out = (float*)d_out;
  float* ws = (float*)d_ws;
  ushort_t* xt     = (ushort_t*)ws;
  ushort_t* mbbf   = (ushort_t*)(ws + MBBF_F);
  ushort_t* keybf  = (ushort_t*)(ws + KEYBF_F);
  ushort_t* rawtbf = (ushort_t*)(ws + RAWTBF_F);
  ushort_t* wpk    = (ushort_t*)(ws + WPK_F);
  ushort_t* wpq    = (ushort_t*)(ws + WPQ_F);
  ushort_t* wpv    = (ushort_t*)(ws + WPV_F);

  k_prep<<<5476, 256, 0, stream>>>(x, wm, wb, wa, xt, wpk, wpq, wpv);
  k_conv<<<dim3(235, 4), 256, 0, stream>>>(xt, wpk, wpq, wpv, bm, bb, ba,
                                           keybf, mbbf, rawtbf);
  k_attn<<<dim3(18, 4, NSEG), 256, 0, stream>>>(mbbf, keybf, rawtbf,
      ws + YP_F, ws + LP_F);
  k_combine<<<576, 256, 0, stream>>>(x, ws, out);
}

// Round 10
// 147.445 us; speedup vs baseline: 1.1544x; 1.1544x over previous
//
#include <hip/hip_runtime.h>
#include <math.h>

typedef unsigned short ushort_t;
typedef __attribute__((ext_vector_type(8))) short short8;
typedef __attribute__((ext_vector_type(4))) float float4v;

// Problem constants
#define NB 4
#define C 64
#define CR 32
#define HW 2304
#define LTOT 7470
#define LPAD 7472
#define NSEG 12
#define SEG 640     // segs 0-10 = 640 (10 chunks), seg 11 = 430 (6 full + 46 tail)
#define LOG2E 1.44269504088896f

// ---- workspace float offsets ----
// Region A (aliased): conv phase: XT bf16 [33000 px][64 ic] = 2112000 shorts
//                     attn phase: YP + LP
#define YP_F 0            // NSEG*4*2304*64 = 7077888
#define LP_F 7077888      // NSEG*4*2304 = 110592 (end 7188480)
// Persistent region
#define MBBF_F   8985600  // bf16 queries (log2e-scaled) [n][q][32]   294912 sh
#define KEYBF_F  9133056  // bf16 keys [n][l][32]                     956160 sh
#define RAWTBF_F 9611136  // bf16 V^T  [n][c][LPAD]                   1912832 sh
#define WPK_F    10567552 // packed key weights 36 frags*512 sh
#define WPQ_F    10576768 // packed query weights 36*512
#define WPV_F    10585984 // packed value weights 8*512 (end 10588032 = 42.4 MB)

static __device__ __forceinline__ ushort_t f2bf(float f) {
  union { float f; unsigned u; } v; v.f = f;
  unsigned r = v.u + 0x7FFF + ((v.u >> 16) & 1);
  return (ushort_t)(r >> 16);
}

__device__ __forceinline__ float cubicw(float d) {
  float ad = fabsf(d);
  float w1 = (1.25f * ad - 2.25f) * ad * ad + 1.0f;
  float w2 = ((-0.75f * ad + 3.75f) * ad - 6.0f) * ad + 3.0f;
  return ad <= 1.0f ? w1 : (ad < 2.0f ? w2 : 0.0f);
}

// ================= k_prep: ring-zero | pad0 | resize | wpack =================
__global__ __launch_bounds__(256) void k_prep(const float* __restrict__ x,
    const float* __restrict__ wm, const float* __restrict__ wb,
    const float* __restrict__ wa, ushort_t* __restrict__ xt,
    ushort_t* __restrict__ wpk, ushort_t* __restrict__ wpq,
    ushort_t* __restrict__ wpv) {
  __shared__ float tile[64][49];
  int bx = blockIdx.x, t = threadIdx.x;

  if (bx < 98) {
    int item = bx * 256 + t;
    if (item < 24960) {
      int pxslot = item >> 3, c8 = item & 7;
      int n = pxslot / 780, rr = pxslot % 780;
      int Dp, PDD, pixb, r;
      if (rr < 196)      { Dp = 50; PDD = 2500; pixb = 0;     r = rr; }
      else if (rr < 372) { Dp = 45; PDD = 2025; pixb = 10000; r = rr - 196; }
      else if (rr < 528) { Dp = 40; PDD = 1600; pixb = 18100; r = rr - 372; }
      else if (rr < 664) { Dp = 35; PDD = 1225; pixb = 24500; r = rr - 528; }
      else               { Dp = 30; PDD = 900;  pixb = 29400; r = rr - 664; }
      int py, px;
      if (r < Dp)            { py = 0; px = r; }
      else if (r < 2 * Dp)   { py = Dp - 1; px = r - Dp; }
      else { int s = r - 2 * Dp; py = 1 + (s >> 1); px = (s & 1) ? Dp - 1 : 0; }
      uint4 z = {0u, 0u, 0u, 0u};
      *(uint4*)(xt + ((size_t)(pixb + n * PDD + py * Dp + px)) * 64 + c8 * 8) = z;
    }
  } else if (bx < 290) {
    int pb = bx - 98;
    int py = pb % 48, n = pb / 48;
#pragma unroll
    for (int i = 0; i < 12; i++) {
      int idx = i * 256 + t;
      int c = idx / 48, px = idx % 48;
      tile[c][px] = x[(size_t)(n * 64 + c) * HW + py * 48 + px];
    }
    __syncthreads();
#pragma unroll
    for (int i = 0; i < 12; i++) {
      int idx = i * 256 + t;
      int c = idx & 63, px = idx >> 6;
      xt[(size_t)(n * 2500 + (py + 1) * 50 + px + 1) * 64 + c] = f2bf(tile[c][px]);
    }
  } else if (bx < 5456) {
    int tid = (bx - 290) * 256 + t;
    if (tid >= 1322496) return;
    int D, Dp, PDD, rem, pixb;
    if (tid < 473344)       { D = 43; Dp = 45; PDD = 2025; rem = tid;           pixb = 10000; }
    else if (tid < 843008)  { D = 38; Dp = 40; PDD = 1600; rem = tid - 473344;  pixb = 18100; }
    else if (tid < 1121792) { D = 33; Dp = 35; PDD = 1225; rem = tid - 843008;  pixb = 24500; }
    else                    { D = 28; Dp = 30; PDD = 900;  rem = tid - 1121792; pixb = 29400; }
    int DD = D * D;
    int pix = rem % DD, nc = rem / DD;
    int py = pix / D, px = pix % D;
    float scale = 48.0f / (float)D;
    float sy = ((float)py + 0.5f) * scale - 0.5f;
    float sx = ((float)px + 0.5f) * scale - 0.5f;
    float y0f = floorf(sy), x0f = floorf(sx);
    int y0 = (int)y0f, x0 = (int)x0f;
    float ty = sy - y0f, tx = sx - x0f;
    float wy[4], wxv[4];
#pragma unroll
    for (int k = 0; k < 4; k++) {
      wy[k]  = cubicw(ty - (float)(k - 1));
      wxv[k] = cubicw(tx - (float)(k - 1));
    }
    const float* src = x + (size_t)nc * HW;
    float acc = 0.f;
#pragma unroll
    for (int dy = 0; dy < 4; ++dy) {
      int iy = min(max(y0 - 1 + dy, 0), 47);
      const float* row = src + iy * 48;
      float a = 0.f;
#pragma unroll
      for (int dx = 0; dx < 4; ++dx) {
        int ix = min(max(x0 - 1 + dx, 0), 47);
        a = fmaf(wxv[dx], row[ix], a);
      }
      acc = fmaf(wy[dy], a, acc);
    }
    int n = nc >> 6, c = nc & 63;
    xt[(size_t)(pixb + n * PDD + (py + 1) * Dp + (px + 1)) * 64 + c] = f2bf(acc);
  } else {
    int tid = (bx - 5456) * 256 + t;
    if (tid >= 5120) return;
    int lane = tid & 63, col = lane & 15, kg = lane >> 4;
    if (tid < 4608) {
      int f = (tid >> 6) % 36;
      bool isq = tid >= 2304;
      int tap = f >> 2, half = (f >> 1) & 1, crt = f & 1;
      int cr = crt * 16 + col;
      int ic0 = half * 32 + kg * 8;
      const float* w = isq ? wb : wm;
      short8 v;
#pragma unroll
      for (int j = 0; j < 8; j++) v[j] = (short)f2bf(w[cr * 576 + (ic0 + j) * 9 + tap]);
      *(short8*)((isq ? wpq : wpk) + (size_t)f * 512 + lane * 8) = v;
    } else {
      int id = tid - 4608;
      int f = id >> 6;
      int half = f >> 2, vt = f & 3;
      int c = vt * 16 + col, ic0 = half * 32 + kg * 8;
      short8 v;
#pragma unroll
      for (int j = 0; j < 8; j++) v[j] = (short)f2bf(wa[c * 64 + ic0 + j]);
      *(short8*)(wpv + (size_t)f * 512 + lane * 8) = v;
    }
  }
}

// ================= all convs as implicit-GEMM MFMA =================
__global__ __launch_bounds__(256) void k_conv(const ushort_t* __restrict__ xt,
    const ushort_t* __restrict__ wpk, const ushort_t* __restrict__ wpq,
    const ushort_t* __restrict__ wpv, const float* __restrict__ bm,
    const float* __restrict__ bb, const float* __restrict__ ba,
    ushort_t* __restrict__ keybf, ushort_t* __restrict__ mbbf,
    ushort_t* __restrict__ rawtbf) {
  int t = threadIdx.x;
  int unit = blockIdx.x * 4 + (t >> 6);
  if (unit >= 938) return;
  int lane = t & 63, col = lane & 15, quad = lane >> 4;
  int n = blockIdx.y;
  int tile = unit >> 1, crt = unit & 1;
  int D, Dp, PDD, DD, pixb, lb, tloc;
  if (tile < 144)      { D = 48; Dp = 50; PDD = 2500; DD = 2304; pixb = 0;     lb = 0;    tloc = tile; }
  else if (tile < 260) { D = 43; Dp = 45; PDD = 2025; DD = 1849; pixb = 10000; lb = 2304; tloc = tile - 144; }
  else if (tile < 351) { D = 38; Dp = 40; PDD = 1600; DD = 1444; pixb = 18100; lb = 4153; tloc = tile - 260; }
  else if (tile < 420) { D = 33; Dp = 35; PDD = 1225; DD = 1089; pixb = 24500; lb = 5597; tloc = tile - 351; }
  else                 { D = 28; Dp = 30; PDD = 900;  DD = 784;  pixb = 29400; lb = 6686; tloc = tile - 420; }
  bool lvl0 = (tile < 144);

  int p = tloc * 16 + col;
  int pv = min(p, DD - 1);
  int py = pv / D, px = pv - py * D;
  const ushort_t* xb = xt + ((size_t)(pixb + n * PDD + (py + 1) * Dp + (px + 1))) * 64 + quad * 8;

  float4v Dk = {0.f, 0.f, 0.f, 0.f};
  float4v Dq = {0.f, 0.f, 0.f, 0.f};
  float4v Dv0 = {0.f, 0.f, 0.f, 0.f};
  float4v Dv1 = {0.f, 0.f, 0.f, 0.f};

#pragma unroll
  for (int dy = -1; dy <= 1; dy++) {
#pragma unroll
    for (int dx = -1; dx <= 1; dx++) {
      int tap = (dy + 1) * 3 + (dx + 1);
      const ushort_t* ab = xb + (dy * Dp + dx) * 64;
#pragma unroll
      for (int half = 0; half < 2; half++) {
        short8 A = *(const short8*)(ab + half * 32);
        int f = (tap * 2 + half) * 2 + crt;
        short8 Bk = *(const short8*)(wpk + (size_t)f * 512 + lane * 8);
        Dk = __builtin_amdgcn_mfma_f32_16x16x32_bf16(A, Bk, Dk, 0, 0, 0);
        if (lvl0) {
          short8 Bq = *(const short8*)(wpq + (size_t)f * 512 + lane * 8);
          Dq = __builtin_amdgcn_mfma_f32_16x16x32_bf16(A, Bq, Dq, 0, 0, 0);
        }
        if (tap == 4) {
          short8 Bv0 = *(const short8*)(wpv + (size_t)(half * 4 + crt * 2) * 512 + lane * 8);
          short8 Bv1 = *(const short8*)(wpv + (size_t)(half * 4 + crt * 2 + 1) * 512 + lane * 8);
          Dv0 = __builtin_amdgcn_mfma_f32_16x16x32_bf16(A, Bv0, Dv0, 0, 0, 0);
          Dv1 = __builtin_amdgcn_mfma_f32_16x16x32_bf16(A, Bv1, Dv1, 0, 0, 0);
        }
      }
    }
  }

  float biask = bm[crt * 16 + col];
  float biasq = bb[crt * 16 + col];
  float biasv0 = ba[crt * 32 + col];
  float biasv1 = ba[crt * 32 + 16 + col];
  int prow = tloc * 16 + quad * 4;
#pragma unroll
  for (int r = 0; r < 4; r++) {
    if (prow + r < DD) {
      int l = lb + prow + r;
      keybf[(size_t)(n * LTOT + l) * 32 + crt * 16 + col] = f2bf(Dk[r] + biask);
      if (lvl0) mbbf[(size_t)(n * HW + l) * 32 + crt * 16 + col] = f2bf((Dq[r] + biasq) * LOG2E);
      rawtbf[(size_t)(n * 64 + crt * 32 + col) * LPAD + l] = f2bf(Dv0[r] + biasv0);
      rawtbf[(size_t)(n * 64 + crt * 32 + 16 + col) * LPAD + l] = f2bf(Dv1[r] + biasv1);
    }
  }
}

// ================= MFMA flash attention v2r: staged V + K/V prefetch =================
// grid (18 q-tiles of 128, 4 n, NSEG). Block 256 = 4 waves; wave owns 32 q.
// S^T = mfma(K,Q) puts l in the register dim -> P stored [q][l] with b64
// writes, read back as b128 A-frags for PV. K frags from global with
// register prefetch one chunk ahead; V double-buffered in LDS (reg
// prefetch); one barrier per chunk.
__global__ __launch_bounds__(256, 4) void k_attn(const ushort_t* __restrict__ mb,
    const ushort_t* __restrict__ keyb, const ushort_t* __restrict__ rawt,
    float* __restrict__ Yp, float* __restrict__ lp) {
  __shared__ __align__(16) ushort_t VsF[2][4096];
  __shared__ __align__(16) ushort_t Pq[4][32 * 72];

  int t = threadIdx.x;
  int n = blockIdx.y, seg = blockIdx.z;
  int lane = t & 63, wv = t >> 6;
  int col = lane & 15, quad = lane >> 4;
  int qb = blockIdx.x * 128 + wv * 32;
  int l_begin = seg * SEG;
  int l_end = min(l_begin + SEG, LTOT);
  int nfull = (l_end - l_begin) >> 6;
  int rem = (l_end - l_begin) & 63;
  int nch = nfull + (rem ? 1 : 0);

  const ushort_t* keyn = keyb + (size_t)n * LTOT * CR;
  const ushort_t* rawn = rawt + (size_t)n * C * LPAD;

  short8 qA0 = *(const short8*)(mb + ((size_t)(n * HW + qb + col)) * CR + quad * 8);
  short8 qA1 = *(const short8*)(mb + ((size_t)(n * HW + qb + 16 + col)) * CR + quad * 8);

  int ct0 = (t >> 6) & 3, g0 = (t >> 4) & 3, cc0 = t & 15;
  size_t so0 = (size_t)(ct0 * 16 + cc0) * LPAD + g0 * 8;
  const ushort_t* kbase = keyn + (size_t)col * CR + quad * 8;

  float4v Y0[4], Y1[4];
#pragma unroll
  for (int ct = 0; ct < 4; ct++)
#pragma unroll
    for (int r = 0; r < 4; r++) { Y0[ct][r] = 0.f; Y1[ct][r] = 0.f; }
  float ls0 = 0.f, ls1 = 0.f;
  const float4v zero4 = {0.f, 0.f, 0.f, 0.f};
  ushort_t* Pw = Pq[wv];

  // preload chunk 0: V staging regs + K frags
  uint4 va = *(const uint4*)(rawn + so0 + l_begin);
  uint4 vb = *(const uint4*)(rawn + so0 + 32 + l_begin);
  short8 kfc[4];
#pragma unroll
  for (int tt = 0; tt < 4; tt++)
    kfc[tt] = *(const short8*)(kbase + (size_t)(l_begin + tt * 16) * CR);
  int buf = 0;

  for (int ch = 0; ch < nch; ++ch) {
    int l0 = l_begin + ch * 64;
    *(uint4*)&VsF[buf][t * 8] = va;
    *(uint4*)&VsF[buf][(t + 256) * 8] = vb;
    // prefetch next chunk's V + K while computing this one
    short8 kfn[4];
    if (ch + 1 < nch) {
      int ln = l0 + 64;
      va = *(const uint4*)(rawn + so0 + ln);
      vb = *(const uint4*)(rawn + so0 + 32 + ln);
#pragma unroll
      for (int tt = 0; tt < 4; tt++)
        kfn[tt] = *(const short8*)(kbase + (size_t)(ln + tt * 16) * CR);
    }
    __syncthreads();

    bool tail = (rem != 0) && (ch == nfull);
#pragma unroll
    for (int tt = 0; tt < 4; tt++) {
      float4v S0 = __builtin_amdgcn_mfma_f32_16x16x32_bf16(kfc[tt], qA0, zero4, 0, 0, 0);
      float4v S1 = __builtin_amdgcn_mfma_f32_16x16x32_bf16(kfc[tt], qA1, zero4, 0, 0, 0);
      int lbase = tt * 16 + quad * 4;
      float p0[4], p1[4];
#pragma unroll
      for (int r = 0; r < 4; r++) {
        bool ok = !tail || (lbase + r < rem);
        float a = __builtin_amdgcn_exp2f(S0[r]);
        float b = __builtin_amdgcn_exp2f(S1[r]);
        p0[r] = ok ? a : 0.f;
        p1[r] = ok ? b : 0.f;
        ls0 += p0[r];
        ls1 += p1[r];
      }
      union { float f; unsigned u; } c0, c1;
      uint2 w;
      c0.f = p0[0]; c1.f = p0[1];
      w.x = ((c0.u + 0x8000u) >> 16) | ((c1.u + 0x8000u) & 0xFFFF0000u);
      c0.f = p0[2]; c1.f = p0[3];
      w.y = ((c0.u + 0x8000u) >> 16) | ((c1.u + 0x8000u) & 0xFFFF0000u);
      *(uint2*)&Pw[col * 72 + lbase] = w;
      c0.f = p1[0]; c1.f = p1[1];
      w.x = ((c0.u + 0x8000u) >> 16) | ((c1.u + 0x8000u) & 0xFFFF0000u);
      c0.f = p1[2]; c1.f = p1[3];
      w.y = ((c0.u + 0x8000u) >> 16) | ((c1.u + 0x8000u) & 0xFFFF0000u);
      *(uint2*)&Pw[(16 + col) * 72 + lbase] = w;
    }

#pragma unroll
    for (int kt = 0; kt < 2; kt++) {
      short8 a0 = *(const short8*)&Pw[col * 72 + kt * 32 + quad * 8];
      short8 a1 = *(const short8*)&Pw[(16 + col) * 72 + kt * 32 + quad * 8];
#pragma unroll
      for (int ct = 0; ct < 4; ct++) {
        short8 bV = *(const short8*)&VsF[buf][(((kt << 2) | ct) * 64 + lane) * 8];
        Y0[ct] = __builtin_amdgcn_mfma_f32_16x16x32_bf16(a0, bV, Y0[ct], 0, 0, 0);
        Y1[ct] = __builtin_amdgcn_mfma_f32_16x16x32_bf16(a1, bV, Y1[ct], 0, 0, 0);
      }
    }
#pragma unroll
    for (int tt = 0; tt < 4; tt++) kfc[tt] = kfn[tt];
    buf ^= 1;
  }

  ls0 += __shfl_xor(ls0, 16); ls0 += __shfl_xor(ls0, 32);
  ls1 += __shfl_xor(ls1, 16); ls1 += __shfl_xor(ls1, 32);

  float* yo = Yp + ((size_t)(seg * NB + n) * HW + qb) * C;
#pragma unroll
  for (int ct = 0; ct < 4; ct++)
#pragma unroll
    for (int r = 0; r < 4; r++) {
      yo[(quad * 4 + r) * C + ct * 16 + col] = Y0[ct][r];
      yo[(16 + quad * 4 + r) * C + ct * 16 + col] = Y1[ct][r];
    }
  if (quad == 0) {
    int base = (seg * NB + n) * HW + qb;
    lp[base + col] = ls0;
    lp[base + 16 + col] = ls1;
  }
}

// ================= combine segment partials + residual =================
__global__ void k_combine(const float* __restrict__ x, const float* __restrict__ ws,
                          float* __restrict__ out) {
  int tid = blockIdx.x * 256 + threadIdx.x;
  int c = tid & 63;
  int t2 = tid >> 6;
  int q = t2 % HW;
  int n = t2 / HW;
  const float* Yv = ws + YP_F;
  const float* lpv = ws + LP_F;
  int i0 = n * HW + q;
  float den = 0.f, num = 0.f;
#pragma unroll
  for (int s = 0; s < NSEG; s++) {
    int idx = s * NB * HW + i0;
    den += lpv[idx];
    num += Yv[(size_t)idx * C + c];
  }
  int oi = (n * C + c) * HW + q;
  out[oi] = num / den + x[oi];
}

extern "C" void kernel_launch(void* const* d_in, const int* in_sizes, int n_in,
                              void* d_out, int out_size, void* d_ws, size_t ws_size,
                              hipStream_t stream) {
  const float* x  = (const float*)d_in[0];
  const float* wb = (const float*)d_in[1];
  const float* bb = (const float*)d_in[2];
  const float* wm = (const float*)d_in[3];
  const float* bm = (const float*)d_in[4];
  const float* wa = (const float*)d_in[5];
  const float* ba = (const float*)d_in[6];
  float* out = (float*)d_out;
  float* ws = (float*)d_ws;
  ushort_t* xt     = (ushort_t*)ws;
  ushort_t* mbbf   = (ushort_t*)(ws + MBBF_F);
  ushort_t* keybf  = (ushort_t*)(ws + KEYBF_F);
  ushort_t* rawtbf = (ushort_t*)(ws + RAWTBF_F);
  ushort_t* wpk    = (ushort_t*)(ws + WPK_F);
  ushort_t* wpq    = (ushort_t*)(ws + WPQ_F);
  ushort_t* wpv    = (ushort_t*)(ws + WPV_F);

  k_prep<<<5476, 256, 0, stream>>>(x, wm, wb, wa, xt, wpk, wpq, wpv);
  k_conv<<<dim3(235, 4), 256, 0, stream>>>(xt, wpk, wpq, wpv, bm, bb, ba,
                                           keybf, mbbf, rawtbf);
  k_attn<<<dim3(18, 4, NSEG), 256, 0, stream>>>(mbbf, keybf, rawtbf,
      ws + YP_F, ws + LP_F);
  k_combine<<<2304, 256, 0, stream>>>(x, ws, out);
}